// Round 7
// baseline (775.609 us; speedup 1.0000x reference)
//
#include <hip/hip_runtime.h>
#include <hip/hip_bf16.h>

// GeomEncoder: B=2048, N=100 nodes, D=256, 4 dense-GAT layers.
// 1024 threads (16 waves) per batch-block, 1 block/CU.
// 32x32x16 MFMA, wave = (Mtile, Npair): 32 nodes x 64 feats per wave.
// W pre-swizzled into MFMA-B fragment order (wbf2) for coalesced streaming.

typedef __attribute__((ext_vector_type(8)))  short bf16x8;   // 8 bf16 = 4 VGPRs
typedef __attribute__((ext_vector_type(4)))  short bf16x4;   // 8 bytes
typedef __attribute__((ext_vector_type(4)))  float f32x4;
typedef __attribute__((ext_vector_type(16))) float f32x16;   // 32x32 MFMA C/D

__device__ __forceinline__ float bf2f(unsigned short u) {
    return __uint_as_float(((unsigned)u) << 16);
}
__device__ __forceinline__ short f2bfs(float f) {
    __hip_bfloat16 h = __float2bfloat16(f);   // RNE
    return *reinterpret_cast<short*>(&h);
}

// ---- LDS layout (bytes) ----
// Hs : [100][256] bf16, row stride 512B, XOR swz   -> 51200
// GsT: [256 feat][128 node] bf16, stride 256B, swz -> 65536
// P  : [128][128] bf16, stride 256B, swz           -> 32768
// SS/SD: 128 f32 each                              -> 1024
#define HS_OFF 0
#define GT_OFF 51200
#define P_OFF  116736
#define SS_OFF 149504
#define SD_OFF 150016
#define SMEM_BYTES 150528

__device__ __forceinline__ int hs_addr(int row, int col) {
    return HS_OFF + row * 512 + ((col * 2) ^ ((row & 7) << 4));
}
__device__ __forceinline__ int gt_addr(int o, int n) {
    return GT_OFF + o * 256 + ((n * 2) ^ ((o & 7) << 4));
}
__device__ __forceinline__ int p_addr(int i, int j) {
    return P_OFF + i * 256 + ((j * 2) ^ ((i & 7) << 4));
}

struct LayerPtrs {
    const float* w[4];
    const float* bias[4];
};
struct PrepPtrs {
    const float* w[4];
    const float* as_[4];
    const float* ad_[4];
};

// ws[l] = W_l^T a_src_l, wd[l] = W_l^T a_dst_l (batch-independent) -> d_ws bf16
__global__ __launch_bounds__(256) void prep_kernel(PrepPtrs p, unsigned short* wsd) {
    const int l = blockIdx.x;
    const int d = threadIdx.x;
    __shared__ float As[256], Ad[256];
    As[d] = p.as_[l][d];
    Ad[d] = p.ad_[l][d];
    __syncthreads();
    const float* W = p.w[l];
    float s1 = 0.f, s2 = 0.f;
    for (int o = 0; o < 256; ++o) {
        float wv = W[o * 256 + d];
        s1 = fmaf(wv, As[o], s1);
        s2 = fmaf(wv, Ad[o], s2);
    }
    wsd[l * 512 + d]       = (unsigned short)f2bfs(s1);
    wsd[l * 512 + 256 + d] = (unsigned short)f2bfs(s2);
}

// W in 32x32x16 MFMA B-fragment order:
// wbf2[(((l*8+nt)*16+ks)*64 + lane)*8 + e] = bf16(W_l[nt*32+(lane&31)][ks*16+(lane>>5)*8+e])
__global__ __launch_bounds__(64) void prep_wfrag_kernel(PrepPtrs p, unsigned short* wbf2) {
    const int bid  = blockIdx.x;            // 512 = 4l * 8nt * 16ks
    const int l    = bid >> 7;
    const int nt   = (bid >> 4) & 7;
    const int ks   = bid & 15;
    const int lane = threadIdx.x;
    const int o    = nt * 32 + (lane & 31);
    const int kb   = ks * 16 + (lane >> 5) * 8;
    const float* W = p.w[l];
    bf16x8 v;
#pragma unroll
    for (int e = 0; e < 8; ++e) v[e] = f2bfs(W[o * 256 + kb + e]);
    *(bf16x8*)(wbf2 + ((size_t)bid * 64 + lane) * 8) = v;
}

__global__ __launch_bounds__(1024) void geom_kernel(
    const float* __restrict__ x,        // [B,100,6]
    const float* __restrict__ remap_w,  // [256,6]
    const float* __restrict__ remap_b,  // [256]
    LayerPtrs lp,
    const unsigned short* __restrict__ wsd,   // score vectors (bf16)
    const unsigned short* __restrict__ wbf2,  // frag-ordered W (bf16, may be null)
    float* __restrict__ out)            // [B,100,256]
{
    extern __shared__ char smem[];
    const int tid  = threadIdx.x;
    const int lane = tid & 63;
    const int wv   = tid >> 6;     // 0..15
    const int hi   = lane >> 5;    // 0..1 (k-group)
    const int ln   = lane & 31;    // MFMA row/col
    const int mt   = wv >> 2;      // M-tile 0..3 (nodes mt*32..+31)
    const int np   = wv & 3;       // N-pair 0..3 (feats np*64..+63)
    const int b    = blockIdx.x;

    const int o0 = np * 64 + ln;   // this lane's feature col, tile 0
    const int o1 = o0 + 32;        // tile 1

    // --- remap: h = relu(x @ remap_w^T + remap_b) ---
    {
        const int o = tid & 255, quarter = tid >> 8;
        float rw[6];
#pragma unroll
        for (int i = 0; i < 6; ++i) rw[i] = remap_w[o * 6 + i];
        const float rb = remap_b[o];
        const float* xb = x + (size_t)b * 600;
        for (int n = quarter * 25; n < quarter * 25 + 25; ++n) {
            float v = rb;
#pragma unroll
            for (int i = 0; i < 6; ++i) v = fmaf(xb[n * 6 + i], rw[i], v);
            v = fmaxf(v, 0.f);
            *(unsigned short*)(smem + hs_addr(n, o)) = (unsigned short)f2bfs(v);
        }
    }

    for (int l = 0; l < 4; ++l) {
        __syncthreads();   // Hs ready; GsT/P/scores free

        // ---------- phase A: g = h @ W^T -> GsT; scores fused on np==0 waves ----------
        {
            f32x16 acc0, acc1, accS;
#pragma unroll
            for (int i = 0; i < 16; ++i) { acc0[i] = 0.f; acc1[i] = 0.f; accS[i] = 0.f; }
            int arow = mt * 32 + ln;
            if (arow > 99) arow = 99;     // clamped tail (finite; masked downstream)
#pragma unroll
            for (int ks = 0; ks < 16; ++ks) {
                bf16x8 a = *(const bf16x8*)(smem + hs_addr(arow, ks * 16 + hi * 8));
                bf16x8 b0, b1;
                if (wbf2) {
                    const unsigned short* wp =
                        wbf2 + (((size_t)(l * 8 + 2 * np) * 16 + ks) * 64 + lane) * 8;
                    b0 = *(const bf16x8*)(wp);
                    b1 = *(const bf16x8*)(wp + 16 * 64 * 8);   // next N-tile
                } else {
                    const float* W = lp.w[l];
#pragma unroll
                    for (int e = 0; e < 8; ++e) {
                        b0[e] = f2bfs(W[o0 * 256 + ks * 16 + hi * 8 + e]);
                        b1[e] = f2bfs(W[o1 * 256 + ks * 16 + hi * 8 + e]);
                    }
                }
                acc0 = __builtin_amdgcn_mfma_f32_32x32x16_bf16(a, b0, acc0, 0, 0, 0);
                acc1 = __builtin_amdgcn_mfma_f32_32x32x16_bf16(a, b1, acc1, 0, 0, 0);
                if (np == 0) {
                    const unsigned short* wsp = wsd + l * 512 + ks * 16 + hi * 8;
                    bf16x8 bs = *(const bf16x8*)(wsp);
                    bf16x8 bd = *(const bf16x8*)(wsp + 256);
                    bf16x8 bz = {0, 0, 0, 0, 0, 0, 0, 0};
                    bf16x8 bb = (ln == 0) ? bs : ((ln == 1) ? bd : bz);
                    accS = __builtin_amdgcn_mfma_f32_32x32x16_bf16(a, bb, accS, 0, 0, 0);
                }
            }
            // GsT writes: reg j -> node row (j&3)+8*(j>>2)+4*hi within M-tile
#pragma unroll
            for (int g4 = 0; g4 < 4; ++g4) {
                bf16x4 v0, v1;
#pragma unroll
                for (int jj = 0; jj < 4; ++jj) {
                    v0[jj] = f2bfs(acc0[g4 * 4 + jj]);
                    v1[jj] = f2bfs(acc1[g4 * 4 + jj]);
                }
                const int node = mt * 32 + 8 * g4 + 4 * hi;
                *(bf16x4*)(smem + gt_addr(o0, node)) = v0;
                *(bf16x4*)(smem + gt_addr(o1, node)) = v1;
            }
            // score writes (lanes holding col 0 = src, col 1 = dst)
            if (np == 0 && ln < 2) {
                float* dst = (float*)(smem + (ln == 0 ? SS_OFF : SD_OFF));
#pragma unroll
                for (int reg = 0; reg < 16; ++reg) {
                    const int row = mt * 32 + (reg & 3) + 8 * (reg >> 2) + 4 * hi;
                    if (row < 100) dst[row] = accS[reg];
                }
            }
        }
        __syncthreads();   // GsT, SS/SD ready

        // ---------- softmax over sources j per target i (8 lanes/row, 128 rows) ----------
        {
            const int i = tid >> 3, s3 = tid & 7;
            if (i < 100) {
                const float sd = ((float*)(smem + SD_OFF))[i];
                const float* Ssf = (const float*)(smem + SS_OFF);
                float vals[2][8];
                float mx = -1e30f;
#pragma unroll
                for (int t = 0; t < 2; ++t) {
                    const int blk = t * 8 + s3;
#pragma unroll
                    for (int e = 0; e < 8; ++e) {
                        const int j = blk * 8 + e;
                        float v;
                        if (j < 100) {
                            float z = sd + Ssf[j];
                            v = (z > 0.f) ? z : 0.2f * z;   // leaky_relu 0.2
                        } else {
                            v = -1e30f;                      // pad -> exp 0
                        }
                        vals[t][e] = v;
                        mx = fmaxf(mx, v);
                    }
                }
                mx = fmaxf(mx, __shfl_xor(mx, 1, 8));
                mx = fmaxf(mx, __shfl_xor(mx, 2, 8));
                mx = fmaxf(mx, __shfl_xor(mx, 4, 8));
                float sum = 0.f;
#pragma unroll
                for (int t = 0; t < 2; ++t)
#pragma unroll
                    for (int e = 0; e < 8; ++e) {
                        float ev = __expf(vals[t][e] - mx);
                        vals[t][e] = ev;
                        sum += ev;
                    }
                sum += __shfl_xor(sum, 1, 8);
                sum += __shfl_xor(sum, 2, 8);
                sum += __shfl_xor(sum, 4, 8);
                const float inv = 1.f / sum;
#pragma unroll
                for (int t = 0; t < 2; ++t) {
                    const int blk = t * 8 + s3;
                    bf16x8 pv;
#pragma unroll
                    for (int e = 0; e < 8; ++e) pv[e] = f2bfs(vals[t][e] * inv);
                    *(bf16x8*)(smem + p_addr(i, blk * 8)) = pv;
                }
            } else {
                bf16x8 z = {0, 0, 0, 0, 0, 0, 0, 0};
#pragma unroll
                for (int t = 0; t < 2; ++t)
                    *(bf16x8*)(smem + p_addr(i, (t * 8 + s3) * 8)) = z;
            }
        }
        __syncthreads();   // P ready

        // ---------- PV: out = attn @ g (+bias, +residual, relu) ----------
        {
            f32x16 c0, c1;
#pragma unroll
            for (int i = 0; i < 16; ++i) { c0[i] = 0.f; c1[i] = 0.f; }
            const int prow = mt * 32 + ln;
#pragma unroll
            for (int ks = 0; ks < 8; ++ks) {
                bf16x8 a  = *(const bf16x8*)(smem + p_addr(prow, ks * 16 + hi * 8));
                bf16x8 b0 = *(const bf16x8*)(smem + gt_addr(o0, ks * 16 + hi * 8));
                bf16x8 b1 = *(const bf16x8*)(smem + gt_addr(o1, ks * 16 + hi * 8));
                c0 = __builtin_amdgcn_mfma_f32_32x32x16_bf16(a, b0, c0, 0, 0, 0);
                c1 = __builtin_amdgcn_mfma_f32_32x32x16_bf16(a, b1, c1, 0, 0, 0);
            }
            const float bia0 = lp.bias[l][o0];
            const float bia1 = lp.bias[l][o1];
            if (l < 3) {
#pragma unroll
                for (int reg = 0; reg < 16; ++reg) {
                    const int row = mt * 32 + (reg & 3) + 8 * (reg >> 2) + 4 * hi;
                    if (row < 100) {
                        {
                            const int ad = hs_addr(row, o0);
                            float r = bf2f(*(unsigned short*)(smem + ad));
                            *(unsigned short*)(smem + ad) =
                                (unsigned short)f2bfs(fmaxf(c0[reg] + bia0 + r, 0.f));
                        }
                        {
                            const int ad = hs_addr(row, o1);
                            float r = bf2f(*(unsigned short*)(smem + ad));
                            *(unsigned short*)(smem + ad) =
                                (unsigned short)f2bfs(fmaxf(c1[reg] + bia1 + r, 0.f));
                        }
                    }
                }
            } else {
                float* ob = out + (size_t)b * 25600;
#pragma unroll
                for (int reg = 0; reg < 16; ++reg) {
                    const int row = mt * 32 + (reg & 3) + 8 * (reg >> 2) + 4 * hi;
                    if (row < 100) {
                        ob[row * 256 + o0] = c0[reg] + bia0;   // 32 lanes -> 128B full line
                        ob[row * 256 + o1] = c1[reg] + bia1;
                    }
                }
            }
        }
    }
}

extern "C" void kernel_launch(void* const* d_in, const int* in_sizes, int n_in,
                              void* d_out, int out_size, void* d_ws, size_t ws_size,
                              hipStream_t stream) {
    const float* x       = (const float*)d_in[0];
    const float* remap_w = (const float*)d_in[2];
    const float* remap_b = (const float*)d_in[3];
    PrepPtrs pp;
    LayerPtrs lp;
    for (int l = 0; l < 4; ++l) {
        lp.w[l]    = pp.w[l]   = (const float*)d_in[4 + 4 * l];
        pp.as_[l]  = (const float*)d_in[5 + 4 * l];
        pp.ad_[l]  = (const float*)d_in[6 + 4 * l];
        lp.bias[l] = (const float*)d_in[7 + 4 * l];
    }
    unsigned short* wsd = (unsigned short*)d_ws;
    // frag-ordered bf16 W right after wsd (4 KB): 4 x 65536 bf16 = 512 KB
    unsigned short* wbf2 = nullptr;
    if (ws_size >= (size_t)(4096 + 4 * 65536 * 2)) {
        wbf2 = (unsigned short*)((char*)d_ws + 4096);
    }

    prep_kernel<<<4, 256, 0, stream>>>(pp, wsd);
    if (wbf2) prep_wfrag_kernel<<<512, 64, 0, stream>>>(pp, wbf2);

    (void)hipFuncSetAttribute(reinterpret_cast<const void*>(geom_kernel),
                              hipFuncAttributeMaxDynamicSharedMemorySize, SMEM_BYTES);
    geom_kernel<<<2048, 1024, SMEM_BYTES, stream>>>(x, remap_w, remap_b, lp, wsd, wbf2,
                                                    (float*)d_out);
}